// Round 1
// baseline (658.995 us; speedup 1.0000x reference)
//
#include <hip/hip_runtime.h>

// Problem: HMM forward over B=64 batches, T=512 steps, S=35 states, D=2496.
// Stage 1: emission GEMM (bf16 MFMA, memory-bound on 327MB obs read)
// Stage 2: per-batch sequential recursion in linear space using the
//          closed-form sparse transition structure.

#define ROWS 32768   // B*T
#define KD   2496    // flattened frame dim
#define NS   35
#define SPAD 48      // padded states (3 MFMA n-tiles of 16)
#define ES   40      // emis row stride (floats)
#define TT   512

typedef short v8s __attribute__((ext_vector_type(8)));
typedef float v4f __attribute__((ext_vector_type(4)));

__device__ inline unsigned short f2bf(float f) {
    unsigned u = __builtin_bit_cast(unsigned, f);
    u += 0x7fffu + ((u >> 16) & 1u);   // RNE
    return (unsigned short)(u >> 16);
}

__device__ inline float wave_max(float v) {
#pragma unroll
    for (int o = 32; o; o >>= 1) v = fmaxf(v, __shfl_xor(v, o, 64));
    return v;
}
__device__ inline float wave_sum(float v) {
#pragma unroll
    for (int o = 32; o; o >>= 1) v += __shfl_xor(v, o, 64);
    return v;
}

// ---- Prep: bf16-convert obs_matrix (zero-pad to 48 states) + m_sq ----
__global__ __launch_bounds__(256) void prep_kernel(
        const float* __restrict__ m, unsigned short* __restrict__ mb,
        float* __restrict__ msq) {
    int s = blockIdx.x;           // 0..47
    int tid = threadIdx.x;
    float part = 0.f;
    for (int k = tid; k < KD; k += 256) {
        float v = (s < NS) ? m[s * KD + k] : 0.f;
        mb[s * KD + k] = f2bf(v);
        part += v * v;
    }
    __shared__ float red[256];
    red[tid] = part;
    __syncthreads();
    for (int off = 128; off > 0; off >>= 1) {
        if (tid < off) red[tid] += red[tid + off];
        __syncthreads();
    }
    if (tid == 0) msq[s] = red[0];
}

// ---- Emission GEMM: emis[row][s] = (|x|^2 + |m_s|^2 - 2 x.m_s)/(-500) ----
// Block: 256 thr = 4 waves, BM=64 rows, BK=64 k-chunk, bf16 MFMA 16x16x32.
__global__ __launch_bounds__(256) void emis_kernel(
        const float* __restrict__ x, const unsigned short* __restrict__ mb,
        const float* __restrict__ msq, float* __restrict__ emis) {
    __shared__ short ldsA[64 * 72];       // bf16 A-tile, stride 72 (pad)
    __shared__ float sqpart[256];
    __shared__ float xsq[64];

    const int tid = threadIdx.x;
    const int row0 = blockIdx.x * 64;
    const int r = tid >> 2, c = tid & 3;  // staging: 4 threads per row
    const int lane = tid & 63, w = tid >> 6;
    const int fm = lane & 15, q = lane >> 4;

    v4f acc[3] = {};
    float sq = 0.f;

    for (int kc = 0; kc < KD / 64; ++kc) {
        const int k0 = kc * 64;
        // stage 64x64 fp32 -> bf16 LDS, accumulate |x|^2 partials
#pragma unroll
        for (int i = 0; i < 4; ++i) {
            const int kl = 4 * c + 16 * i;
            const float4 v = *(const float4*)&x[(long)(row0 + r) * KD + k0 + kl];
            sq += v.x * v.x + v.y * v.y + v.z * v.z + v.w * v.w;
            unsigned lo = (unsigned)f2bf(v.x) | ((unsigned)f2bf(v.y) << 16);
            unsigned hi = (unsigned)f2bf(v.z) | ((unsigned)f2bf(v.w) << 16);
            *(uint2*)&ldsA[r * 72 + kl] = make_uint2(lo, hi);
        }
        __syncthreads();
        // compute: 2 MFMA k-steps per chunk, 3 n-tiles
#pragma unroll
        for (int ks = 0; ks < 2; ++ks) {
            v8s a = *(const v8s*)&ldsA[(w * 16 + fm) * 72 + ks * 32 + q * 8];
#pragma unroll
            for (int nt = 0; nt < 3; ++nt) {
                const int st = nt * 16 + fm;
                v8s b = *(const v8s*)&mb[st * KD + k0 + ks * 32 + q * 8];
                acc[nt] = __builtin_amdgcn_mfma_f32_16x16x32_bf16(a, b, acc[nt], 0, 0, 0);
            }
        }
        __syncthreads();
    }

    sqpart[tid] = sq;
    __syncthreads();
    if (tid < 64)
        xsq[tid] = sqpart[tid * 4] + sqpart[tid * 4 + 1] +
                   sqpart[tid * 4 + 2] + sqpart[tid * 4 + 3];
    __syncthreads();

    // epilogue: D layout col = lane&15, row = (lane>>4)*4 + reg
#pragma unroll
    for (int nt = 0; nt < 3; ++nt) {
        const int st = nt * 16 + fm;
        if (st < NS) {
            const float ms = msq[st];
#pragma unroll
            for (int rg = 0; rg < 4; ++rg) {
                const int rl = w * 16 + q * 4 + rg;
                emis[(long)(row0 + rl) * ES + st] =
                    (xsq[rl] + ms - 2.f * acc[nt][rg]) * (-1.f / 500.f);
            }
        }
    }
}

// ---- Forward recursion: one wave per batch, linear-space sparse matvec ----
// T = 0.1 I + 0.8 shift1 + 0.08 shift2 + (0.02/35) ones  (rows sum to 1)
// alpha'[j] = e[j] + M + log(0.1 p_j + 0.8 p_{j-1} + 0.08 p_{j-2} + cb*S)
// with p = exp(alpha - M), S = sum p.  alpha non-increasing => stale M safe.
__global__ __launch_bounds__(64) void forward_kernel(
        const float* __restrict__ emis, float* __restrict__ out) {
    const int b = blockIdx.x;
    const int j = threadIdx.x;
    const bool act = j < NS;
    const float LOG2E = 1.4426950408889634f, LN2 = 0.6931471805599453f;
    const float c0 = 0.1f, c1 = 0.8f, c2 = 0.08f, cb = 0.02f / 35.f;

    const float* eb = emis + (long)b * TT * ES;
    const float prior = (j == 0) ? 10.f : -10.f;
    float alpha = act ? (eb[j] + prior) : -3.0e38f;
    const int s1 = (j + 34) % 35, s2 = (j + 33) % 35;

    float M = wave_max(alpha);
    float e_next = eb[ES + j];
    for (int t = 1; t < TT; ++t) {
        const float ecur = e_next;
        const int tn = (t + 1 < TT) ? (t + 1) : (TT - 1);
        e_next = eb[tn * ES + j];               // prefetch next step
        if ((t & 3) == 0) M = wave_max(alpha);  // refresh scale every 4 steps
        const float p = act ? __builtin_amdgcn_exp2f((alpha - M) * LOG2E) : 0.f;
        const float S = wave_sum(p);
        const float pm1 = __shfl(p, s1, 64);
        const float pm2 = __shfl(p, s2, 64);
        const float s = c0 * p + c1 * pm1 + c2 * pm2 + cb * S;
        const float na = ecur + M + LN2 * __builtin_amdgcn_logf(s);
        alpha = act ? na : -3.0e38f;
    }
    M = wave_max(alpha);
    const float p = act ? __builtin_amdgcn_exp2f((alpha - M) * LOG2E) : 0.f;
    const float S = wave_sum(p);
    if (j == 0) out[b] = M + LN2 * __builtin_amdgcn_logf(S);
}

extern "C" void kernel_launch(void* const* d_in, const int* in_sizes, int n_in,
                              void* d_out, int out_size, void* d_ws, size_t ws_size,
                              hipStream_t stream) {
    const float* obs  = (const float*)d_in[0];   // [64,512,16,13,12] fp32
    const float* obsm = (const float*)d_in[1];   // [35,16,13,12] fp32
    float* out = (float*)d_out;                  // [64] fp32

    char* ws = (char*)d_ws;
    float* emis = (float*)ws;                                  // 32768*40*4 = 5,242,880 B
    unsigned short* mb = (unsigned short*)(ws + 5242880);      // 48*2496*2  =   239,616 B
    float* msq = (float*)(ws + 5482496);                       // 48*4

    prep_kernel<<<SPAD, 256, 0, stream>>>(obsm, mb, msq);
    emis_kernel<<<ROWS / 64, 256, 0, stream>>>(obs, mb, msq, emis);
    forward_kernel<<<64, 64, 0, stream>>>(emis, out);
}

// Round 2
// 562.402 us; speedup vs baseline: 1.1718x; 1.1718x over previous
//
#include <hip/hip_runtime.h>

// HMM forward: B=64, T=512, S=35, D=2496.
// emis: bf16 MFMA GEMM, register-double-buffered staging (memory-bound, 327MB).
// forward: linear-space recursion p' = E_t * (A p), DPP reductions, log-free chain.

#define ROWS 32768   // B*T
#define KD   2496
#define NS   35
#define SPAD 48
#define ES   40      // emis row stride (floats)
#define TT   512

typedef short v8s __attribute__((ext_vector_type(8)));
typedef float v4f __attribute__((ext_vector_type(4)));

__device__ __forceinline__ unsigned short f2bf(float f) {
    unsigned u = __builtin_bit_cast(unsigned, f);
    u += 0x7fffu + ((u >> 16) & 1u);   // RNE
    return (unsigned short)(u >> 16);
}

// ---- DPP cross-lane reduce (VALU-latency, no LDS pipe) ----
template <int CTRL, int RM>
__device__ __forceinline__ float dppf(float oldv, float v) {
    return __builtin_bit_cast(float, __builtin_amdgcn_update_dpp(
        __builtin_bit_cast(int, oldv), __builtin_bit_cast(int, v),
        CTRL, RM, 0xf, false));
}

__device__ __forceinline__ float wsum63(float v) {   // total broadcast via lane 63
    v += dppf<0x111, 0xf>(0.f, v);   // row_shr:1
    v += dppf<0x112, 0xf>(0.f, v);   // row_shr:2
    v += dppf<0x114, 0xf>(0.f, v);   // row_shr:4
    v += dppf<0x118, 0xf>(0.f, v);   // row_shr:8
    v += dppf<0x142, 0xa>(0.f, v);   // row_bcast:15 -> rows 1,3
    v += dppf<0x143, 0xc>(0.f, v);   // row_bcast:31 -> rows 2,3
    return __builtin_bit_cast(float,
        __builtin_amdgcn_readlane(__builtin_bit_cast(int, v), 63));
}

__device__ __forceinline__ float wmax63(float v) {
    const float NI = -3.0e38f;
    v = fmaxf(v, dppf<0x111, 0xf>(NI, v));
    v = fmaxf(v, dppf<0x112, 0xf>(NI, v));
    v = fmaxf(v, dppf<0x114, 0xf>(NI, v));
    v = fmaxf(v, dppf<0x118, 0xf>(NI, v));
    v = fmaxf(v, dppf<0x142, 0xa>(NI, v));
    v = fmaxf(v, dppf<0x143, 0xc>(NI, v));
    return __builtin_bit_cast(float,
        __builtin_amdgcn_readlane(__builtin_bit_cast(int, v), 63));
}

// ---- Prep: bf16-convert obs_matrix (zero-pad to 48 states) + m_sq ----
__global__ __launch_bounds__(256) void prep_kernel(
        const float* __restrict__ m, unsigned short* __restrict__ mb,
        float* __restrict__ msq) {
    int s = blockIdx.x;
    int tid = threadIdx.x;
    float part = 0.f;
    for (int k = tid; k < KD; k += 256) {
        float v = (s < NS) ? m[s * KD + k] : 0.f;
        mb[s * KD + k] = f2bf(v);
        part += v * v;
    }
    __shared__ float red[256];
    red[tid] = part;
    __syncthreads();
    for (int off = 128; off > 0; off >>= 1) {
        if (tid < off) red[tid] += red[tid + off];
        __syncthreads();
    }
    if (tid == 0) msq[s] = red[0];
}

// ---- Emission GEMM, register-double-buffered. BM=64, BK=96 (26 chunks). ----
__global__ __launch_bounds__(256) void emis_kernel(
        const float* __restrict__ x, const unsigned short* __restrict__ mb,
        const float* __restrict__ msq, float* __restrict__ emis) {
    __shared__ short ldsA[64 * 104];     // stride 104 shorts: 2-way-only conflicts
    __shared__ float sqpart[256];
    __shared__ float xsq[64];

    const int tid = threadIdx.x;
    const int row0 = blockIdx.x * 64;
    const int r = tid >> 2, c = tid & 3;     // staging: 4 threads per row
    const int lane = tid & 63, w = tid >> 6;
    const int fm = lane & 15, q = lane >> 4;
    const float* xr = x + (long)(row0 + r) * KD;

    float4 va[6];
#pragma unroll
    for (int i = 0; i < 6; ++i) va[i] = *(const float4*)&xr[4 * c + 16 * i];

    v4f acc[3] = {};
    float sq = 0.f;

    for (int kc = 0; kc < 26; ++kc) {
        const int k0 = kc * 96;
        // B fragments for this chunk (L2-resident), issued before convert
        v8s breg[3][3];
#pragma unroll
        for (int ks = 0; ks < 3; ++ks)
#pragma unroll
            for (int nt = 0; nt < 3; ++nt)
                breg[ks][nt] = *(const v8s*)&mb[(nt * 16 + fm) * KD + k0 + ks * 32 + q * 8];
        // convert prefetched A regs -> LDS, accumulate |x|^2
#pragma unroll
        for (int i = 0; i < 6; ++i) {
            const float4 v = va[i];
            sq += v.x * v.x + v.y * v.y + v.z * v.z + v.w * v.w;
            unsigned lo = (unsigned)f2bf(v.x) | ((unsigned)f2bf(v.y) << 16);
            unsigned hi = (unsigned)f2bf(v.z) | ((unsigned)f2bf(v.w) << 16);
            *(uint2*)&ldsA[r * 104 + 4 * c + 16 * i] = make_uint2(lo, hi);
        }
        __syncthreads();
        // prefetch next A chunk (overlaps with MFMA below)
        if (kc + 1 < 26) {
            const float* xn = xr + (kc + 1) * 96;
#pragma unroll
            for (int i = 0; i < 6; ++i) va[i] = *(const float4*)&xn[4 * c + 16 * i];
        }
        // MFMA: 3 k-steps x 3 n-tiles
#pragma unroll
        for (int ks = 0; ks < 3; ++ks) {
            v8s a = *(const v8s*)&ldsA[(w * 16 + fm) * 104 + ks * 32 + q * 8];
#pragma unroll
            for (int nt = 0; nt < 3; ++nt)
                acc[nt] = __builtin_amdgcn_mfma_f32_16x16x32_bf16(a, breg[ks][nt], acc[nt], 0, 0, 0);
        }
        __syncthreads();
    }

    sqpart[tid] = sq;
    __syncthreads();
    if (tid < 64)
        xsq[tid] = sqpart[tid * 4] + sqpart[tid * 4 + 1] +
                   sqpart[tid * 4 + 2] + sqpart[tid * 4 + 3];
    __syncthreads();

#pragma unroll
    for (int nt = 0; nt < 3; ++nt) {
        const int st = nt * 16 + fm;
        if (st < NS) {
            const float ms = msq[st];
#pragma unroll
            for (int rg = 0; rg < 4; ++rg) {
                const int rl = w * 16 + q * 4 + rg;
                emis[(long)(row0 + rl) * ES + st] =
                    (xsq[rl] + ms - 2.f * acc[nt][rg]) * (-1.f / 500.f);
            }
        }
    }
}

// ---- Forward recursion, linear space, log-free chain ----
// p'_j = exp(e_j - mx) * (0.1 p_j + 0.8 p_{j-1} + 0.08 p_{j-2} + cb*S), C += mx
// S = sum_j p_j (needed for the uniform term anyway); renorm by S every 8 steps.
__global__ __launch_bounds__(64) void forward_kernel(
        const float* __restrict__ emis, float* __restrict__ out) {
    const int b = blockIdx.x;
    const int j = threadIdx.x;
    const bool act = j < NS;
    const float LOG2E = 1.4426950408889634f, LN2 = 0.6931471805599453f;
    const float c0 = 0.1f, c1 = 0.8f, c2 = 0.08f, cb = 0.02f / 35.f;
    const float NI = -3.0e38f;

    const float* eb = emis + (long)b * TT * ES;
    const int s1 = (j + 34) % 35, s2 = (j + 33) % 35;

    const float e0 = act ? eb[j] : NI;
    const float a0 = e0 + ((j == 0) ? 10.f : -10.f);
    float C = wmax63(act ? a0 : NI);
    float p = act ? __builtin_amdgcn_exp2f((a0 - C) * LOG2E) : 0.f;

    float e_nx = eb[ES + j];    // e for t=1 (prefetch)
    for (int t = 1; t < TT; ++t) {
        const float ecur = e_nx;
        const int tn = (t + 1 < TT) ? (t + 1) : t;
        e_nx = eb[tn * ES + j];
        // off-chain: per-step emission scale (independent of p)
        const float mx = wmax63(act ? ecur : NI);
        const float E = __builtin_amdgcn_exp2f((ecur - mx) * LOG2E);
        // chain: sparse matvec in linear space
        const float pm1 = __shfl(p, s1, 64);
        const float pm2 = __shfl(p, s2, 64);
        const float S = wsum63(p);
        float s = fmaf(c0, p, cb * S);
        s = fmaf(c1, pm1, s);
        s = fmaf(c2, pm2, s);
        p = act ? (E * s) : 0.f;
        C += mx;
        if ((t & 7) == 0) {      // renorm (S shrinks >= cb per step, never 0)
            p *= 1.0f / S;
            C += LN2 * __builtin_amdgcn_logf(S);
        }
    }
    const float Sf = wsum63(p);
    if (j == 0) out[b] = C + LN2 * __builtin_amdgcn_logf(Sf);
}

extern "C" void kernel_launch(void* const* d_in, const int* in_sizes, int n_in,
                              void* d_out, int out_size, void* d_ws, size_t ws_size,
                              hipStream_t stream) {
    const float* obs  = (const float*)d_in[0];
    const float* obsm = (const float*)d_in[1];
    float* out = (float*)d_out;

    char* ws = (char*)d_ws;
    float* emis = (float*)ws;                               // 32768*40*4 = 5,242,880 B
    unsigned short* mb = (unsigned short*)(ws + 5242880);   // 48*2496*2  =   239,616 B
    float* msq = (float*)(ws + 5482496);                    // 48*4

    prep_kernel<<<SPAD, 256, 0, stream>>>(obsm, mb, msq);
    emis_kernel<<<ROWS / 64, 256, 0, stream>>>(obs, mb, msq, emis);
    forward_kernel<<<64, 64, 0, stream>>>(emis, out);
}

// Round 3
// 523.588 us; speedup vs baseline: 1.2586x; 1.0741x over previous
//
#include <hip/hip_runtime.h>

// HMM forward: B=64, T=512, S=35, D=2496.
// emis: bf16 MFMA GEMM, NO LDS / NO BARRIERS — direct global->register
//       fragment loads, 6-chunk-deep A double-buffer, 1-chunk B double-buffer.
// forward: linear-space recursion p' = E_t (A p), DPP reductions, 8-deep
//       e-prefetch, log-free chain.

#define ROWS 32768   // B*T
#define KD   2496
#define NS   35
#define SPAD 48
#define ES   40      // emis row stride (floats)
#define TT   512

typedef short v8s __attribute__((ext_vector_type(8)));
typedef float v4f __attribute__((ext_vector_type(4)));

__device__ __forceinline__ unsigned short f2bf(float f) {
    unsigned u = __builtin_bit_cast(unsigned, f);
    u += 0x7fffu + ((u >> 16) & 1u);   // RNE
    return (unsigned short)(u >> 16);
}

// ---- DPP cross-lane reduce (VALU-latency, no LDS pipe) ----
template <int CTRL, int RM>
__device__ __forceinline__ float dppf(float oldv, float v) {
    return __builtin_bit_cast(float, __builtin_amdgcn_update_dpp(
        __builtin_bit_cast(int, oldv), __builtin_bit_cast(int, v),
        CTRL, RM, 0xf, false));
}

__device__ __forceinline__ float wsum63(float v) {
    v += dppf<0x111, 0xf>(0.f, v);   // row_shr:1
    v += dppf<0x112, 0xf>(0.f, v);   // row_shr:2
    v += dppf<0x114, 0xf>(0.f, v);   // row_shr:4
    v += dppf<0x118, 0xf>(0.f, v);   // row_shr:8
    v += dppf<0x142, 0xa>(0.f, v);   // row_bcast:15
    v += dppf<0x143, 0xc>(0.f, v);   // row_bcast:31
    return __builtin_bit_cast(float,
        __builtin_amdgcn_readlane(__builtin_bit_cast(int, v), 63));
}

__device__ __forceinline__ float wmax63(float v) {
    const float NI = -3.0e38f;
    v = fmaxf(v, dppf<0x111, 0xf>(NI, v));
    v = fmaxf(v, dppf<0x112, 0xf>(NI, v));
    v = fmaxf(v, dppf<0x114, 0xf>(NI, v));
    v = fmaxf(v, dppf<0x118, 0xf>(NI, v));
    v = fmaxf(v, dppf<0x142, 0xa>(NI, v));
    v = fmaxf(v, dppf<0x143, 0xc>(NI, v));
    return __builtin_bit_cast(float,
        __builtin_amdgcn_readlane(__builtin_bit_cast(int, v), 63));
}

// ---- Prep: bf16-convert obs_matrix (zero-pad to 48 states) + m_sq ----
__global__ __launch_bounds__(256) void prep_kernel(
        const float* __restrict__ m, unsigned short* __restrict__ mb,
        float* __restrict__ msq) {
    int s = blockIdx.x;
    int tid = threadIdx.x;
    float part = 0.f;
    for (int k = tid; k < KD; k += 256) {
        float v = (s < NS) ? m[s * KD + k] : 0.f;
        mb[s * KD + k] = f2bf(v);
        part += v * v;
    }
    __shared__ float red[256];
    red[tid] = part;
    __syncthreads();
    for (int off = 128; off > 0; off >>= 1) {
        if (tid < off) red[tid] += red[tid + off];
        __syncthreads();
    }
    if (tid == 0) msq[s] = red[0];
}

// ---- Emission GEMM, barrier-free. Wave = 16 rows x 48 states, K streamed ----
__global__ __launch_bounds__(256) void emis_kernel(
        const float* __restrict__ x, const unsigned short* __restrict__ mb,
        const float* __restrict__ msq, float* __restrict__ emis) {
    const int tid = threadIdx.x;
    const int lane = tid & 63, w = tid >> 6;
    const int fm = lane & 15, q = lane >> 4;
    const int row0 = blockIdx.x * 64 + w * 16;          // this wave's row tile
    const float* xr = x + (long)(row0 + fm) * KD + q * 8;     // lane A stream
    const unsigned short* mb0 = mb + (long)fm * KD + q * 8;   // lane B stream

    v4f acc[3] = {};
    float sq = 0.f;

    float4 cur[6][2], nxt[6][2];
#pragma unroll
    for (int i = 0; i < 6; ++i) {
        cur[i][0] = *(const float4*)&xr[i * 32];
        cur[i][1] = *(const float4*)&xr[i * 32 + 4];
    }
    v8s bc[3], bn[3];
#pragma unroll
    for (int nt = 0; nt < 3; ++nt)
        bc[nt] = *(const v8s*)&mb0[nt * 16 * KD];

    for (int g = 0; g < 13; ++g) {                      // 13 groups x 6 chunks
        const int kbase = g * 192;
        if (g + 1 < 13) {
            const float* xn = xr + kbase + 192;
#pragma unroll
            for (int i = 0; i < 6; ++i) {
                nxt[i][0] = *(const float4*)&xn[i * 32];
                nxt[i][1] = *(const float4*)&xn[i * 32 + 4];
            }
        }
#pragma unroll
        for (int i = 0; i < 6; ++i) {
            const int knext = kbase + (i + 1) * 32;     // B double-buffer
            if (knext < KD) {
#pragma unroll
                for (int nt = 0; nt < 3; ++nt)
                    bn[nt] = *(const v8s*)&mb0[nt * 16 * KD + knext];
            }
            const float4 v0 = cur[i][0], v1 = cur[i][1];
            sq += v0.x * v0.x + v0.y * v0.y + v0.z * v0.z + v0.w * v0.w
                + v1.x * v1.x + v1.y * v1.y + v1.z * v1.z + v1.w * v1.w;
            v8s a;
            a[0] = (short)f2bf(v0.x); a[1] = (short)f2bf(v0.y);
            a[2] = (short)f2bf(v0.z); a[3] = (short)f2bf(v0.w);
            a[4] = (short)f2bf(v1.x); a[5] = (short)f2bf(v1.y);
            a[6] = (short)f2bf(v1.z); a[7] = (short)f2bf(v1.w);
#pragma unroll
            for (int nt = 0; nt < 3; ++nt)
                acc[nt] = __builtin_amdgcn_mfma_f32_16x16x32_bf16(a, bc[nt], acc[nt], 0, 0, 0);
#pragma unroll
            for (int nt = 0; nt < 3; ++nt) bc[nt] = bn[nt];
        }
#pragma unroll
        for (int i = 0; i < 6; ++i) {
            cur[i][0] = nxt[i][0];
            cur[i][1] = nxt[i][1];
        }
    }

    // |x_row|^2: lane holds partial over k = q*8 .. ; reduce across q-groups
    float s2 = sq + __shfl_xor(sq, 16, 64);
    s2 += __shfl_xor(s2, 32, 64);        // lane (fm,q): full |x_{row0+fm}|^2
    float xs[4];
#pragma unroll
    for (int rg = 0; rg < 4; ++rg)
        xs[rg] = __shfl(s2, q * 4 + rg, 64);   // xsq of output row q*4+rg

    // D layout: col = lane&15 -> state, row = q*4+reg -> x-row
#pragma unroll
    for (int nt = 0; nt < 3; ++nt) {
        const int st = nt * 16 + fm;
        if (st < NS) {
            const float ms = msq[st];
#pragma unroll
            for (int rg = 0; rg < 4; ++rg) {
                emis[(long)(row0 + q * 4 + rg) * ES + st] =
                    (xs[rg] + ms - 2.f * acc[nt][rg]) * (-1.f / 500.f);
            }
        }
    }
}

// ---- Forward recursion, linear space, 8-deep e-prefetch ----
__global__ __launch_bounds__(64) void forward_kernel(
        const float* __restrict__ emis, float* __restrict__ out) {
    const int b = blockIdx.x;
    const int j = threadIdx.x;
    const bool act = j < NS;
    const int jc = act ? j : NS - 1;
    const float LOG2E = 1.4426950408889634f, LN2 = 0.6931471805599453f;
    const float c0 = 0.1f, c1 = 0.8f, c2 = 0.08f, cb = 0.02f / 35.f;
    const float NI = -3.0e38f;

    const float* ebj = emis + (long)b * TT * ES + jc;
    const int s1 = (j + 34) % 35, s2 = (j + 33) % 35;

    const float e0 = ebj[0];
    const float a0 = (act ? e0 : NI) + ((j == 0) ? 10.f : -10.f);
    float C = wmax63(act ? a0 : NI);
    float p = act ? __builtin_amdgcn_exp2f((a0 - C) * LOG2E) : 0.f;

    float cur[8], nxt[8];
#pragma unroll
    for (int i = 0; i < 8; ++i) cur[i] = ebj[(1 + i) * ES];   // t = 1..8

    for (int g = 0; g < 63; ++g) {
        const int tb = 9 + 8 * g;
#pragma unroll
        for (int i = 0; i < 8; ++i) {
            const int t = tb + i;
            nxt[i] = ebj[(t < TT ? t : TT - 1) * ES];
        }
        float S = 1.f;
#pragma unroll
        for (int i = 0; i < 8; ++i) {
            const float e = cur[i];
            const float mx = wmax63(act ? e : NI);            // off-chain
            const float E = act ? __builtin_amdgcn_exp2f((e - mx) * LOG2E) : 0.f;
            const float pm1 = __shfl(p, s1, 64);
            const float pm2 = __shfl(p, s2, 64);
            S = wsum63(p);
            const float u = fmaf(c1, pm1, c2 * pm2);
            const float v = fmaf(c0, p, cb * S);
            p = E * (u + v);
            C += mx;
        }
        p *= 1.f / S;                 // exact renorm bookkeeping
        C += LN2 * __builtin_amdgcn_logf(S);
#pragma unroll
        for (int i = 0; i < 8; ++i) cur[i] = nxt[i];
    }
    // tail: t = 505..511
#pragma unroll
    for (int i = 0; i < 7; ++i) {
        const float e = cur[i];
        const float mx = wmax63(act ? e : NI);
        const float E = act ? __builtin_amdgcn_exp2f((e - mx) * LOG2E) : 0.f;
        const float pm1 = __shfl(p, s1, 64);
        const float pm2 = __shfl(p, s2, 64);
        const float S = wsum63(p);
        const float u = fmaf(c1, pm1, c2 * pm2);
        const float v = fmaf(c0, p, cb * S);
        p = E * (u + v);
        C += mx;
    }
    const float Sf = wsum63(p);
    if (j == 0) out[b] = C + LN2 * __builtin_amdgcn_logf(Sf);
}

extern "C" void kernel_launch(void* const* d_in, const int* in_sizes, int n_in,
                              void* d_out, int out_size, void* d_ws, size_t ws_size,
                              hipStream_t stream) {
    const float* obs  = (const float*)d_in[0];
    const float* obsm = (const float*)d_in[1];
    float* out = (float*)d_out;

    char* ws = (char*)d_ws;
    float* emis = (float*)ws;                               // 32768*40*4 = 5,242,880 B
    unsigned short* mb = (unsigned short*)(ws + 5242880);   // 48*2496*2  =   239,616 B
    float* msq = (float*)(ws + 5482496);                    // 48*4

    prep_kernel<<<SPAD, 256, 0, stream>>>(obsm, mb, msq);
    emis_kernel<<<ROWS / 64, 256, 0, stream>>>(obs, mb, msq, emis);
    forward_kernel<<<64, 64, 0, stream>>>(emis, out);
}